// Round 11
// baseline (691.837 us; speedup 1.0000x reference)
//
#include <hip/hip_runtime.h>

#define D 4096
#define RANK 1024
#define K2 2048
#define UELEMS 4194304ULL   // D*RANK
#define NTOT 16777216ULL    // 4^12 = D*D
#define QSCALE 16000.0f

typedef __attribute__((ext_vector_type(4))) int i32x4;

__device__ float g_tr[1];      // trace accumulator (zeroed by convert kernel)
__device__ float g_scale[D];
__device__ float g_mdre[16];   // M-dagger: M†[s][i][j] = conj(M[s][j][i])
__device__ float g_mdim[16];

static __device__ __forceinline__ void load_lds16(const void* g, void* l) {
    __builtin_amdgcn_global_load_lds(
        (const __attribute__((address_space(1))) unsigned int*)g,
        (__attribute__((address_space(3))) unsigned int*)l, 16, 0, 0);
}

// ---------------------------------------------------------------------------
// i8 split quantization of W = [Ur | Ui] with per-row scale (verified r6).
// Also builds M† tables and zeroes the trace accumulator.
// ---------------------------------------------------------------------------
__global__ __launch_bounds__(256) void convert_w_i8(const float* __restrict__ P,
                                                    const float* __restrict__ Mre,
                                                    const float* __restrict__ Mim,
                                                    char* __restrict__ Wh,
                                                    char* __restrict__ Wl,
                                                    char* __restrict__ N2h,
                                                    char* __restrict__ N2l)
{
    if (blockIdx.x == 0) {
        if (threadIdx.x < 16) {
            const int s = threadIdx.x >> 2, i = (threadIdx.x >> 1) & 1, j = threadIdx.x & 1;
            g_mdre[threadIdx.x] =  Mre[s * 4 + j * 2 + i];
            g_mdim[threadIdx.x] = -Mim[s * 4 + j * 2 + i];
        }
        if (threadIdx.x == 16) g_tr[0] = 0.f;
    }

    const int w = threadIdx.x >> 6, lane = threadIdx.x & 63;
    const int row = blockIdx.x * 4 + w;

    float ur[16], ui[16];
    const float* pr = P + (size_t)row * RANK + lane * 16;
    const float* pi = P + UELEMS + (size_t)row * RANK + lane * 16;
    #pragma unroll
    for (int q = 0; q < 4; ++q) {
        const float4 a = ((const float4*)pr)[q];
        const float4 b = ((const float4*)pi)[q];
        ur[q * 4 + 0] = a.x; ur[q * 4 + 1] = a.y; ur[q * 4 + 2] = a.z; ur[q * 4 + 3] = a.w;
        ui[q * 4 + 0] = b.x; ui[q * 4 + 1] = b.y; ui[q * 4 + 2] = b.z; ui[q * 4 + 3] = b.w;
    }
    float mx = 0.f;
    #pragma unroll
    for (int e = 0; e < 16; ++e)
        mx = fmaxf(mx, fmaxf(fabsf(ur[e]), fabsf(ui[e])));
    #pragma unroll
    for (int off = 1; off < 64; off <<= 1)
        mx = fmaxf(mx, __shfl_xor(mx, off));
    const float inv = mx > 0.f ? QSCALE / mx : 0.f;
    if (lane == 0) g_scale[row] = mx / QSCALE;

    int hr[16], lr[16], hi[16], li[16];
    #pragma unroll
    for (int e = 0; e < 16; ++e) {
        float q = ur[e] * inv;
        float hf = rintf(q * 0.0078125f);
        hr[e] = (int)hf; lr[e] = (int)rintf(q - 128.f * hf);
        q = ui[e] * inv;
        hf = rintf(q * 0.0078125f);
        hi[e] = (int)hf; li[e] = (int)rintf(q - 128.f * hf);
    }
    uint4 phr, plr, phi, pli, pnh, pnl;
    unsigned* dst[6] = {(unsigned*)&phr, (unsigned*)&plr, (unsigned*)&phi,
                        (unsigned*)&pli, (unsigned*)&pnh, (unsigned*)&pnl};
    #pragma unroll
    for (int q = 0; q < 4; ++q) {
        unsigned a = 0, b = 0, c = 0, d = 0, e = 0, f = 0;
        #pragma unroll
        for (int k = 0; k < 4; ++k) {
            const int sh = k * 8;
            a |= (unsigned)(hr[q * 4 + k] & 255) << sh;
            b |= (unsigned)(lr[q * 4 + k] & 255) << sh;
            c |= (unsigned)(hi[q * 4 + k] & 255) << sh;
            d |= (unsigned)(li[q * 4 + k] & 255) << sh;
            e |= (unsigned)((-hi[q * 4 + k]) & 255) << sh;
            f |= (unsigned)((-li[q * 4 + k]) & 255) << sh;
        }
        dst[0][q] = a; dst[1][q] = b; dst[2][q] = c; dst[3][q] = d; dst[4][q] = e; dst[5][q] = f;
    }
    const size_t b1 = (size_t)row * 2048 + lane * 16;
    *(uint4*)&Wh[b1] = phr;          *(uint4*)&Wl[b1] = plr;
    *(uint4*)&Wh[b1 + 1024] = phi;   *(uint4*)&Wl[b1 + 1024] = pli;
    const size_t b2 = (size_t)row * 1024 + lane * 16;
    *(uint4*)&N2h[b2] = pnh;         *(uint4*)&N2l[b2] = pnl;
}

// ---------------------------------------------------------------------------
// 2-qubit staged contraction on a 4x4 register tile (verified r9/r10).
// ---------------------------------------------------------------------------
static __device__ __forceinline__ void qmt2(float2* x,
                                            const float* __restrict__ Mre,
                                            const float* __restrict__ Mim)
{
    float2 y[16];
    #pragma unroll
    for (int sb = 0; sb < 4; ++sb)
        #pragma unroll
        for (int ja = 0; ja < 2; ++ja)
            #pragma unroll
            for (int ia = 0; ia < 2; ++ia) {
                float2 acc = make_float2(0.f, 0.f);
                #pragma unroll
                for (int ib = 0; ib < 2; ++ib)
                    #pragma unroll
                    for (int jb = 0; jb < 2; ++jb) {
                        const float mr = Mre[sb * 4 + ib * 2 + jb];
                        const float mi = Mim[sb * 4 + ib * 2 + jb];
                        const float2 v = x[(ja * 2 + jb) * 4 + ia * 2 + ib];
                        acc.x += mr * v.x - mi * v.y;
                        acc.y += mr * v.y + mi * v.x;
                    }
                y[sb * 4 + ja * 2 + ia] = acc;
            }
    #pragma unroll
    for (int sa = 0; sa < 4; ++sa)
        #pragma unroll
        for (int sb = 0; sb < 4; ++sb) {
            float2 acc = make_float2(0.f, 0.f);
            #pragma unroll
            for (int ia = 0; ia < 2; ++ia)
                #pragma unroll
                for (int ja = 0; ja < 2; ++ja) {
                    const float mr = Mre[sa * 4 + ia * 2 + ja];
                    const float mi = Mim[sa * 4 + ia * 2 + ja];
                    const float2 v = y[sb * 4 + ja * 2 + ia];
                    acc.x += mr * v.x - mi * v.y;
                    acc.y += mr * v.y + mi * v.x;
                }
            x[sa * 4 + sb] = acc;
        }
}

// ---------------------------------------------------------------------------
// 3-stage 6-qubit pipeline, 2 LDS exchanges (verified r9/r10). Caller must
// sync before reusing X.
// ---------------------------------------------------------------------------
static __device__ __forceinline__ void pA_pipeline(float2* x, float2* X, const int t,
                                                   const float* __restrict__ mre,
                                                   const float* __restrict__ mim)
{
    qmt2(x, mre, mim);
    #pragma unroll
    for (int d = 0; d < 16; ++d) X[t * 17 + d] = x[d];
    __syncthreads();
    const int a2 = t >> 6, t2 = (t >> 4) & 3, d1 = t & 15;
    #pragma unroll
    for (int j2 = 0; j2 < 4; ++j2)
        #pragma unroll
        for (int i2 = 0; i2 < 4; ++i2)
            x[j2 * 4 + i2] = X[((a2 * 4 + j2) * 16 + t2 * 4 + i2) * 17 + d1];
    __syncthreads();
    qmt2(x, mre, mim);
    #pragma unroll
    for (int d = 0; d < 16; ++d) X[(a2 * 4 + t2) * 257 + d * 16 + d1] = x[d];
    __syncthreads();
    const int e2 = t >> 4, e1 = t & 15;
    #pragma unroll
    for (int j2 = 0; j2 < 4; ++j2)
        #pragma unroll
        for (int i2 = 0; i2 < 4; ++i2)
            x[j2 * 4 + i2] = X[(j2 * 4 + i2) * 257 + e2 * 16 + e1];
    qmt2(x, mre, mim);
}

// ---------------------------------------------------------------------------
// FUSED: i8 Hermitian GEMM + 6-LSB-qubit contraction. rho is never written
// to HBM. Triangle blocks (bi 64-row x bj 128-col). Per 64x64 sub-tile
// (skip strictly-upper): reshuffle register fragments -> padded LDS tile,
// load per-thread 4x4 x0, run pipeline with M -> out(rr,cc); off-diagonal
// also with M-dagger -> conj -> out(cc,rr). Diagonal tiles are exact
// (computed re symmetric / im antisymmetric — same W both operands).
// Trace accumulated from diagonal tiles -> atomicAdd(g_tr).
// LDS: one 64 KB pool, aliased (K-loop staging -> Tile -> exchange X).
// ---------------------------------------------------------------------------
__global__ __launch_bounds__(256, 2) void gemm_qmtA(const char* __restrict__ Wh,
                                                    const char* __restrict__ Wl,
                                                    const char* __restrict__ N2h,
                                                    const char* __restrict__ N2l,
                                                    const float* __restrict__ Mre,
                                                    const float* __restrict__ Mim,
                                                    float2* __restrict__ out)
{
    __shared__ __align__(16) char pool[65536];
    char* const sA1h = pool;
    char* const sA1l = pool + 4096;
    char* const sA2h = pool + 8192;
    char* const sA2l = pool + 12288;
    char* const sB1h = pool + 16384;
    char* const sB1l = pool + 24576;
    char* const sB2h = pool + 32768;
    char* const sB2l = pool + 40960;
    char* const sN2h = pool + 49152;
    char* const sN2l = pool + 57344;

    const int b = blockIdx.x;
    int bj = (int)((65.0f - sqrtf(4225.0f - 4.0f * (float)b)) * 0.5f);
    while (bj > 0 && bj * (65 - bj) > b) --bj;
    while ((bj + 1) * (64 - bj) <= b) ++bj;
    const int bi = 2 * bj + (b - bj * (65 - bj));
    const int row0 = bi << 6, col0 = bj << 7;

    const int t = threadIdx.x;
    const int lane = t & 63, w = t >> 6;
    const int wr = w >> 1, wc = w & 1;

    const int rowA = t >> 2;
    const int kcA = (t & 3) ^ ((rowA >> 1) & 3);
    const size_t aoff = (size_t)(row0 + rowA) * 2048 + kcA * 16;
    const int ldsA = t * 16;
    size_t boff[2], boffN[2]; int ldsB[2];
    #pragma unroll
    for (int q = 0; q < 2; ++q) {
        const int g = q * 256 + t;
        const int rowB = g >> 2;
        const int kcB = (g & 3) ^ ((rowB >> 1) & 3);
        boff[q]  = (size_t)(col0 + rowB) * 2048 + kcB * 16;
        boffN[q] = (size_t)(col0 + rowB) * 1024 + kcB * 16;
        ldsB[q] = g * 16;
    }

    const int m = lane & 15, gq = lane >> 4;
    const int fko = (gq ^ ((m >> 1) & 3)) * 16;

    i32x4 rehh[2][4], remx[2][4], imhh[2][4], immx[2][4];
    #pragma unroll
    for (int i = 0; i < 2; ++i)
        #pragma unroll
        for (int j = 0; j < 4; ++j) {
            rehh[i][j] = (i32x4){0, 0, 0, 0}; remx[i][j] = (i32x4){0, 0, 0, 0};
            imhh[i][j] = (i32x4){0, 0, 0, 0}; immx[i][j] = (i32x4){0, 0, 0, 0};
        }

    for (int kt = 0; kt < RANK; kt += 64) {
        load_lds16(Wh + aoff + kt,        sA1h + ldsA);
        load_lds16(Wl + aoff + kt,        sA1l + ldsA);
        load_lds16(Wh + aoff + kt + 1024, sA2h + ldsA);
        load_lds16(Wl + aoff + kt + 1024, sA2l + ldsA);
        #pragma unroll
        for (int q = 0; q < 2; ++q) {
            load_lds16(Wh + boff[q] + kt,        sB1h + ldsB[q]);
            load_lds16(Wl + boff[q] + kt,        sB1l + ldsB[q]);
            load_lds16(Wh + boff[q] + kt + 1024, sB2h + ldsB[q]);
            load_lds16(Wl + boff[q] + kt + 1024, sB2l + ldsB[q]);
            load_lds16(N2h + boffN[q] + kt,      sN2h + ldsB[q]);
            load_lds16(N2l + boffN[q] + kt,      sN2l + ldsB[q]);
        }
        __syncthreads();

        i32x4 fa1h[2], fa1l[2], fa2h[2], fa2l[2];
        #pragma unroll
        for (int i = 0; i < 2; ++i) {
            const int off = (wr * 32 + i * 16 + m) * 64 + fko;
            fa1h[i] = *(const i32x4*)&sA1h[off];
            fa1l[i] = *(const i32x4*)&sA1l[off];
            fa2h[i] = *(const i32x4*)&sA2h[off];
            fa2l[i] = *(const i32x4*)&sA2l[off];
        }
        #pragma unroll
        for (int j = 0; j < 4; ++j) {
            const int off = (wc * 64 + j * 16 + m) * 64 + fko;
            const i32x4 b1h = *(const i32x4*)&sB1h[off];
            const i32x4 b1l = *(const i32x4*)&sB1l[off];
            const i32x4 b2h = *(const i32x4*)&sB2h[off];
            const i32x4 b2l = *(const i32x4*)&sB2l[off];
            const i32x4 n2h = *(const i32x4*)&sN2h[off];
            const i32x4 n2l = *(const i32x4*)&sN2l[off];
            #pragma unroll
            for (int i = 0; i < 2; ++i) {
                i32x4 r = rehh[i][j];
                r = __builtin_amdgcn_mfma_i32_16x16x64_i8(fa1h[i], b1h, r, 0, 0, 0);
                r = __builtin_amdgcn_mfma_i32_16x16x64_i8(fa2h[i], b2h, r, 0, 0, 0);
                rehh[i][j] = r;
                r = remx[i][j];
                r = __builtin_amdgcn_mfma_i32_16x16x64_i8(fa1h[i], b1l, r, 0, 0, 0);
                r = __builtin_amdgcn_mfma_i32_16x16x64_i8(fa1l[i], b1h, r, 0, 0, 0);
                r = __builtin_amdgcn_mfma_i32_16x16x64_i8(fa2h[i], b2l, r, 0, 0, 0);
                r = __builtin_amdgcn_mfma_i32_16x16x64_i8(fa2l[i], b2h, r, 0, 0, 0);
                remx[i][j] = r;
                r = imhh[i][j];
                r = __builtin_amdgcn_mfma_i32_16x16x64_i8(fa2h[i], b1h, r, 0, 0, 0);
                r = __builtin_amdgcn_mfma_i32_16x16x64_i8(fa1h[i], n2h, r, 0, 0, 0);
                imhh[i][j] = r;
                r = immx[i][j];
                r = __builtin_amdgcn_mfma_i32_16x16x64_i8(fa2h[i], b1l, r, 0, 0, 0);
                r = __builtin_amdgcn_mfma_i32_16x16x64_i8(fa2l[i], b1h, r, 0, 0, 0);
                r = __builtin_amdgcn_mfma_i32_16x16x64_i8(fa1h[i], n2l, r, 0, 0, 0);
                r = __builtin_amdgcn_mfma_i32_16x16x64_i8(fa1l[i], n2h, r, 0, 0, 0);
                immx[i][j] = r;
            }
        }
        __syncthreads();
    }

    // ---- fused epilogue: per 64x64 sub-tile, reshuffle + qmt pipeline ----
    float2* const Tile = (float2*)pool;   // 64 x 66 padded (33792 B)
    float2* const X    = (float2*)pool;   // exchange buffer (34816 B), sequential
    float trloc = 0.f;
    const int e2 = t >> 4, e1 = t & 15;
    const int a4 = t >> 4, t4 = t & 15;

    #pragma unroll
    for (int h = 0; h < 2; ++h) {
        const int ccT = 2 * bj + h;
        if (ccT > bi) continue;               // strictly-upper tile: skip (uniform)
        const bool diag = (ccT == bi);

        if (wc == h) {
            #pragma unroll
            for (int i = 0; i < 2; ++i)
                #pragma unroll
                for (int j = 0; j < 4; ++j) {
                    const int col_l = j * 16 + m;
                    const float sc = g_scale[ccT * 64 + col_l];
                    #pragma unroll
                    for (int r = 0; r < 4; ++r) {
                        const int row_l = wr * 32 + i * 16 + gq * 4 + r;
                        const float s2 = g_scale[row0 + row_l] * sc;
                        const float re = s2 * (16384.f * (float)rehh[i][j][r] + 128.f * (float)remx[i][j][r]);
                        const float im = s2 * (16384.f * (float)imhh[i][j][r] + 128.f * (float)immx[i][j][r]);
                        Tile[row_l * 66 + col_l] = make_float2(re, im);
                        if (diag && row_l == col_l) trloc += re;
                    }
                }
        }
        __syncthreads();

        float2 x0[16], x[16];
        #pragma unroll
        for (int j2 = 0; j2 < 4; ++j2) {
            const float4* p = (const float4*)&Tile[(a4 * 4 + j2) * 66 + t4 * 4];
            const float4 v0 = p[0], v1 = p[1];
            x0[j2 * 4 + 0] = make_float2(v0.x, v0.y);
            x0[j2 * 4 + 1] = make_float2(v0.z, v0.w);
            x0[j2 * 4 + 2] = make_float2(v1.x, v1.y);
            x0[j2 * 4 + 3] = make_float2(v1.z, v1.w);
        }
        __syncthreads();   // Tile consumed; X may overwrite

        #pragma unroll
        for (int q = 0; q < 16; ++q) x[q] = x0[q];
        pA_pipeline(x, X, t, Mre, Mim);
        const size_t ob0 = (size_t)(bi * 64 + ccT) * 4096 + e2 * 16 + e1;
        #pragma unroll
        for (int d = 0; d < 16; ++d) out[ob0 + (size_t)d * 256] = x[d];

        if (!diag) {
            __syncthreads();
            #pragma unroll
            for (int q = 0; q < 16; ++q) x[q] = x0[q];
            pA_pipeline(x, X, t, g_mdre, g_mdim);
            const size_t ob1 = (size_t)(ccT * 64 + bi) * 4096 + e2 * 16 + e1;
            #pragma unroll
            for (int d = 0; d < 16; ++d)
                out[ob1 + (size_t)d * 256] = make_float2(x[d].x, -x[d].y);
        }
        __syncthreads();
    }

    // trace: wave-reduce + one atomic per wave (only diag blocks nonzero)
    #pragma unroll
    for (int off = 1; off < 64; off <<= 1) trloc += __shfl_xor(trloc, off);
    if (lane == 0 && trloc != 0.f) atomicAdd(&g_tr[0], trloc);
}

// ---------------------------------------------------------------------------
// Staged 3-qubit contraction (verified r4-r10) — used by p3/p4.
// ---------------------------------------------------------------------------
static __device__ __forceinline__ void qmt_stage_cb(float2* x,
                                                    const float* __restrict__ Mre,
                                                    const float* __restrict__ Mim)
{
    #pragma unroll
    for (int jj = 0; jj < 4; ++jj) {
        float2 y[16];
        #pragma unroll
        for (int sc = 0; sc < 4; ++sc)
            #pragma unroll
            for (int ii = 0; ii < 4; ++ii) {
                float2 acc = make_float2(0.f, 0.f);
                #pragma unroll
                for (int ic = 0; ic < 2; ++ic)
                    #pragma unroll
                    for (int jc = 0; jc < 2; ++jc) {
                        const float mr = Mre[sc * 4 + ic * 2 + jc];
                        const float mi = Mim[sc * 4 + ic * 2 + jc];
                        const float2 v = x[jj * 16 + jc * 8 + ii * 2 + ic];
                        acc.x += mr * v.x - mi * v.y;
                        acc.y += mr * v.y + mi * v.x;
                    }
                y[sc * 4 + ii] = acc;
            }
        #pragma unroll
        for (int q = 0; q < 16; ++q) x[jj * 16 + q] = y[q];
    }

    #pragma unroll
    for (int ja = 0; ja < 2; ++ja)
        #pragma unroll
        for (int sc = 0; sc < 4; ++sc) {
            float2 z[8];
            #pragma unroll
            for (int sb = 0; sb < 4; ++sb)
                #pragma unroll
                for (int ia = 0; ia < 2; ++ia) {
                    float2 acc = make_float2(0.f, 0.f);
                    #pragma unroll
                    for (int ib = 0; ib < 2; ++ib)
                        #pragma unroll
                        for (int jb = 0; jb < 2; ++jb) {
                            const float mr = Mre[sb * 4 + ib * 2 + jb];
                            const float mi = Mim[sb * 4 + ib * 2 + jb];
                            const float2 v = x[(ja * 2 + jb) * 16 + sc * 4 + ia * 2 + ib];
                            acc.x += mr * v.x - mi * v.y;
                            acc.y += mr * v.y + mi * v.x;
                        }
                    z[sb * 2 + ia] = acc;
                }
            #pragma unroll
            for (int sb = 0; sb < 4; ++sb)
                #pragma unroll
                for (int ia = 0; ia < 2; ++ia)
                    x[ja * 32 + (sb >> 1) * 16 + sc * 4 + ia * 2 + (sb & 1)] = z[sb * 2 + ia];
        }
}

#define QMT_STAGE_A(STORE)                                                     \
    _Pragma("unroll")                                                          \
    for (int sbH = 0; sbH < 2; ++sbH)                                          \
        _Pragma("unroll")                                                      \
        for (int sc = 0; sc < 4; ++sc)                                         \
            _Pragma("unroll")                                                  \
            for (int sbL = 0; sbL < 2; ++sbL) {                                \
                const int sb = sbH * 2 + sbL;                                  \
                _Pragma("unroll")                                              \
                for (int sa = 0; sa < 4; ++sa) {                               \
                    float2 acc = make_float2(0.f, 0.f);                        \
                    _Pragma("unroll")                                          \
                    for (int ia = 0; ia < 2; ++ia)                             \
                        _Pragma("unroll")                                      \
                        for (int ja = 0; ja < 2; ++ja) {                       \
                            const float mr = Mre[sa * 4 + ia * 2 + ja];        \
                            const float mi = Mim[sa * 4 + ia * 2 + ja];        \
                            const float2 v = x[ja * 32 + sbH * 16 + sc * 4 + ia * 2 + sbL]; \
                            acc.x += mr * v.x - mi * v.y;                      \
                            acc.y += mr * v.y + mi * v.x;                      \
                        }                                                      \
                    const int s3 = sa * 16 + sb * 4 + sc;                      \
                    STORE;                                                     \
                }                                                              \
            }

// ---------------------------------------------------------------------------
// Pass B (= p3): in [rr(64), cc(64), S(4096)]; out [r3,c3, s3(64), S].
// ---------------------------------------------------------------------------
__global__ __launch_bounds__(256) void qmt_p3(const float2* __restrict__ in,
                                              float2* __restrict__ out,
                                              const float* __restrict__ Mre,
                                              const float* __restrict__ Mim)
{
    const int tid = blockIdx.x * 256 + threadIdx.x;
    const int s = tid & 4095, c3 = (tid >> 12) & 7, r3 = tid >> 15;

    float2 x[64];
    #pragma unroll
    for (int j3 = 0; j3 < 8; ++j3)
        #pragma unroll
        for (int i3 = 0; i3 < 8; ++i3)
            x[j3 * 8 + i3] = in[(size_t)((r3 * 8 + j3) * 64 + c3 * 8 + i3) * 4096 + s];
    qmt_stage_cb(x, Mre, Mim);
    const size_t ob = ((size_t)(r3 * 8 + c3) * 64) * 4096 + s;
    QMT_STAGE_A(out[ob + s3 * 4096] = acc)
}

// ---------------------------------------------------------------------------
// Pass C (= p4, MSB triplet): real-only out [s_hi, s3(64), s_lo(32)].
// ---------------------------------------------------------------------------
__global__ __launch_bounds__(256) void qmt_p4(const float2* __restrict__ in,
                                              float* __restrict__ out,
                                              const float* __restrict__ Mre,
                                              const float* __restrict__ Mim)
{
    const int tid = blockIdx.x * 256 + threadIdx.x;   // 2^18
    float2 x[64];
    #pragma unroll
    for (int j3 = 0; j3 < 8; ++j3)
        #pragma unroll
        for (int i3 = 0; i3 < 8; ++i3)
            x[j3 * 8 + i3] = in[(size_t)(j3 * 8 + i3) * 262144 + tid];
    qmt_stage_cb(x, Mre, Mim);
    const size_t ob = (size_t)(tid >> 5) * 2048 + (tid & 31);
    QMT_STAGE_A(out[ob + s3 * 32] = acc.x)
}

// ---------------------------------------------------------------------------
__global__ void gather_idx(const float* __restrict__ P, const int* __restrict__ idxs,
                           float* __restrict__ out, const int n)
{
    const int i = blockIdx.x * 256 + threadIdx.x;
    if (i < n) {
        const int idx = idxs[i];
        const int s = idx & 262143;
        const size_t pos = (size_t)(s >> 5) * 2048 + (size_t)(idx >> 18) * 32 + (s & 31);
        out[i] = P[pos] * (1.0f / g_tr[0]);
    }
}

// ---------------------------------------------------------------------------
extern "C" void kernel_launch(void* const* d_in, const int* in_sizes, int n_in,
                              void* d_out, int out_size, void* d_ws, size_t ws_size,
                              hipStream_t stream)
{
    const float* params = (const float*)d_in[0];  // (2, D, RANK) fp32
    const float* Mre    = (const float*)d_in[1];
    const float* Mim    = (const float*)d_in[2];
    const int*   idxs   = (const int*)d_in[3];
    float*       out    = (float*)d_out;

    float* ws = (float*)d_ws;
    float2* A  = (float2*)ws;                 // 134 MB plane
    float2* Bp = (float2*)(ws + 2 * NTOT);    // 134 MB plane
    // i8 planes in the B region (dead after the fused GEMM): 25 MB
    char* Wh  = (char*)Bp;
    char* Wl  = Wh + (size_t)D * 2048;
    char* N2h = Wl + (size_t)D * 2048;
    char* N2l = N2h + (size_t)D * 1024;

    convert_w_i8<<<1024, 256, 0, stream>>>(params, Mre, Mim, Wh, Wl, N2h, N2l);
    gemm_qmtA<<<1056, 256, 0, stream>>>(Wh, Wl, N2h, N2l, Mre, Mim, A);  // GEMM + 6 LSB qubits
    qmt_p3<<<1024, 256, 0, stream>>>(A, Bp, Mre, Mim);   // 3 qubits
    qmt_p4<<<1024, 256, 0, stream>>>(Bp, (float*)A, Mre, Mim);  // 3 qubits, real out

    gather_idx<<<(out_size + 255) / 256, 256, 0, stream>>>((float*)A, idxs, out, out_size);
}